// Round 1
// baseline (136.329 us; speedup 1.0000x reference)
//
#include <hip/hip_runtime.h>
#include <math.h>
#include <float.h>

#define B_SZ 512
#define C_SZ 1000
#define D_SZ 512
#define K_TOP 10

// ---------------------------------------------------------------------------
// Kernel 1: rd[c,d] = softmax_d( rowmax - sqrt(N*ex2^2 - ex1^2) )
// rowmax cancels: rd = exp(min(v)-v) / sum(exp(min(v)-v))
// One block (256 threads) per class row; each thread owns 2 of the 512 elems.
// ---------------------------------------------------------------------------
__global__ __launch_bounds__(256) void rd_kernel(const float* __restrict__ ex2,
                                                 const float* __restrict__ ex1,
                                                 const int* __restrict__ cls_num,
                                                 float* __restrict__ rd) {
    __shared__ float sbuf[256];
    const int c = blockIdx.x;
    const int t = threadIdx.x;
    const float N = (float)cls_num[c];
    const float* e2 = ex2 + (size_t)c * D_SZ;
    const float* e1 = ex1 + (size_t)c * D_SZ;

    float a0 = e2[t],       b0 = e1[t];
    float a1 = e2[t + 256], b1 = e1[t + 256];
    float v0 = sqrtf(N * a0 * a0 - b0 * b0);
    float v1 = sqrtf(N * a1 * a1 - b1 * b1);

    // block-min reduce
    sbuf[t] = fminf(v0, v1);
    __syncthreads();
    for (int s = 128; s > 0; s >>= 1) {
        if (t < s) sbuf[t] = fminf(sbuf[t], sbuf[t + s]);
        __syncthreads();
    }
    const float mn = sbuf[0];
    __syncthreads();

    const float e0v = expf(mn - v0);
    const float e1v = expf(mn - v1);

    sbuf[t] = e0v + e1v;
    __syncthreads();
    for (int s = 128; s > 0; s >>= 1) {
        if (t < s) sbuf[t] += sbuf[t + s];
        __syncthreads();
    }
    const float inv = 1.0f / sbuf[0];

    float* o = rd + (size_t)c * D_SZ;
    o[t]       = e0v * inv;
    o[t + 256] = e1v * inv;
}

// ---------------------------------------------------------------------------
// Kernel 2: simi[b,c] = sum_d (x[b,d]-protos[c,d])^2 * rd[c,d]
// Tiled fp32 contraction: block tile 64(B) x 32(C), K-chunk 16,
// 256 threads, 4x2 micro-tile per thread. Grid 32x8 = 256 blocks.
// ---------------------------------------------------------------------------
#define TB 64
#define TC 32
#define BK 16

__global__ __launch_bounds__(256) void dist_kernel(const float* __restrict__ x,
                                                   const float* __restrict__ protos,
                                                   const float* __restrict__ rd,
                                                   float* __restrict__ simi) {
    __shared__ float xs[BK][TB + 1];   // [k][b]
    __shared__ float ps[BK][TC + 1];   // [k][c]
    __shared__ float rs[BK][TC + 1];   // [k][c]

    const int tid = threadIdx.x;
    const int tx = tid & 15;   // c direction (x2)
    const int ty = tid >> 4;   // b direction (x4)
    const int b0 = blockIdx.y * TB;
    const int c0 = blockIdx.x * TC;

    float acc[4][2] = {};

    for (int k0 = 0; k0 < D_SZ; k0 += BK) {
        // x tile: 64 rows x 16 cols = 1024 floats, 4 per thread, coalesced
        #pragma unroll
        for (int i = 0; i < 4; i++) {
            int f = tid + i * 256;
            int row = f >> 4, col = f & 15;
            xs[col][row] = x[(size_t)(b0 + row) * D_SZ + k0 + col];
        }
        // protos / rd tiles: 32 rows x 16 cols = 512 floats, 2 per thread
        #pragma unroll
        for (int i = 0; i < 2; i++) {
            int f = tid + i * 256;
            int row = f >> 4, col = f & 15;
            int cc = c0 + row;
            float pv = 0.f, rv = 0.f;
            if (cc < C_SZ) {
                pv = protos[(size_t)cc * D_SZ + k0 + col];
                rv = rd[(size_t)cc * D_SZ + k0 + col];
            }
            ps[col][row] = pv;
            rs[col][row] = rv;
        }
        __syncthreads();

        #pragma unroll
        for (int kk = 0; kk < BK; kk++) {
            float xv[4], pv[2], rv[2];
            #pragma unroll
            for (int i = 0; i < 4; i++) xv[i] = xs[kk][ty * 4 + i];
            #pragma unroll
            for (int j = 0; j < 2; j++) {
                pv[j] = ps[kk][tx * 2 + j];
                rv[j] = rs[kk][tx * 2 + j];
            }
            #pragma unroll
            for (int i = 0; i < 4; i++)
                #pragma unroll
                for (int j = 0; j < 2; j++) {
                    float d = xv[i] - pv[j];
                    acc[i][j] = fmaf(d * d, rv[j], acc[i][j]);
                }
        }
        __syncthreads();
    }

    #pragma unroll
    for (int i = 0; i < 4; i++) {
        int b = b0 + ty * 4 + i;
        #pragma unroll
        for (int j = 0; j < 2; j++) {
            int c = c0 + tx * 2 + j;
            if (c < C_SZ) simi[(size_t)b * C_SZ + c] = acc[i][j];
        }
    }
}

// ---------------------------------------------------------------------------
// Kernel 3: per-row top-10 smallest (value asc, index tie-break asc),
// conf = sum(vals)/vals, argmax(first) -> proto_label gather.
// One wave (64 lanes) per row; 4 rows per 256-thread block; 128 blocks.
// out[0..B)   : predict (as float)
// out[B...)   : topk_conf row-major [B][K]
// ---------------------------------------------------------------------------
__global__ __launch_bounds__(256) void topk_kernel(const float* __restrict__ simi,
                                                   const int* __restrict__ proto_label,
                                                   float* __restrict__ out) {
    const int wid = threadIdx.x >> 6;
    const int lane = threadIdx.x & 63;
    const int b = blockIdx.x * 4 + wid;

    const float* row = simi + (size_t)b * C_SZ;
    float vals[16];
    #pragma unroll
    for (int j = 0; j < 16; j++) {
        int c = lane + j * 64;
        vals[j] = (c < C_SZ) ? row[c] : FLT_MAX;
    }

    float kv[K_TOP];
    int ki[K_TOP];
    for (int t = 0; t < K_TOP; t++) {
        float bv = FLT_MAX;
        int bi = 0x7fffffff;
        #pragma unroll
        for (int j = 0; j < 16; j++) {
            int c = lane + j * 64;
            if (vals[j] < bv) { bv = vals[j]; bi = c; }
        }
        // 64-lane butterfly min with index tie-break (lower index wins)
        #pragma unroll
        for (int off = 1; off < 64; off <<= 1) {
            float ov = __shfl_xor(bv, off);
            int oi = __shfl_xor(bi, off);
            if (ov < bv || (ov == bv && oi < bi)) { bv = ov; bi = oi; }
        }
        kv[t] = bv;
        ki[t] = bi;
        if ((bi & 63) == lane) vals[bi >> 6] = FLT_MAX;  // remove the winner
    }

    if (lane == 0) {
        float S = 0.f;
        #pragma unroll
        for (int t = 0; t < K_TOP; t++) S += kv[t];
        float conf[K_TOP];
        #pragma unroll
        for (int t = 0; t < K_TOP; t++) {
            conf[t] = S / kv[t];
            out[B_SZ + b * K_TOP + t] = conf[t];
        }
        int best = 0;
        for (int t = 1; t < K_TOP; t++)
            if (conf[t] > conf[best]) best = t;
        out[b] = (float)proto_label[ki[best]];
    }
}

extern "C" void kernel_launch(void* const* d_in, const int* in_sizes, int n_in,
                              void* d_out, int out_size, void* d_ws, size_t ws_size,
                              hipStream_t stream) {
    const float* x           = (const float*)d_in[0];
    const float* protos      = (const float*)d_in[1];
    const float* ex2         = (const float*)d_in[2];
    const float* ex1         = (const float*)d_in[3];
    const int*   cls_num     = (const int*)d_in[4];
    const int*   proto_label = (const int*)d_in[5];

    float* rd   = (float*)d_ws;                 // C*D floats = 2 MB
    float* simi = rd + (size_t)C_SZ * D_SZ;     // B*C floats = 2 MB
    float* out  = (float*)d_out;

    rd_kernel<<<C_SZ, 256, 0, stream>>>(ex2, ex1, cls_num, rd);

    dim3 g2((C_SZ + TC - 1) / TC, B_SZ / TB);   // 32 x 8 = 256 blocks
    dist_kernel<<<g2, 256, 0, stream>>>(x, protos, rd, simi);

    topk_kernel<<<B_SZ / 4, 256, 0, stream>>>(simi, proto_label, out);
}

// Round 2
// 108.256 us; speedup vs baseline: 1.2593x; 1.2593x over previous
//
#include <hip/hip_runtime.h>
#include <math.h>
#include <float.h>

#define B_SZ 512
#define C_SZ 1000
#define D_SZ 512
#define K_TOP 10
#define K2 1024                       // 2*D: [x^2 | x] vs [rd | -2*rd*p]
#define NSPLIT 4
#define KSPLIT (K2 / NSPLIT)          // 256
#define BC (B_SZ * C_SZ)

// ws layout (floats)
#define A_OFF   0                     // B x K2        = 524288
#define W_OFF   (B_SZ * K2)           // C x K2        = 1024000
#define T3_OFF  (W_OFF + C_SZ * K2)   // 1024 (pad)
#define PART_OFF (T3_OFF + 1024)      // NSPLIT x B x C = 2048000
// total ~ 3.6M floats ~ 13.7 MB

// ---------------------------------------------------------------------------
// Prep: one wave per row, butterfly-shuffle reductions (no __syncthreads).
// blocks [0, 250): W rows (4 classes/block):
//   rd = softmax(min-trick), W[c,d]=rd, W[c,D+d]=-2*rd*p, t3[c]=sum rd*p^2
// blocks [250, 378): A rows (4 batch rows/block): A[b,d]=x^2, A[b,D+d]=x
// ---------------------------------------------------------------------------
__global__ __launch_bounds__(256) void prep_kernel(const float* __restrict__ x,
                                                   const float* __restrict__ protos,
                                                   const float* __restrict__ ex2,
                                                   const float* __restrict__ ex1,
                                                   const int* __restrict__ cls_num,
                                                   float* __restrict__ ws) {
    float* A  = ws + A_OFF;
    float* W  = ws + W_OFF;
    float* t3 = ws + T3_OFF;
    const int wid  = threadIdx.x >> 6;
    const int lane = threadIdx.x & 63;
    const int blk  = blockIdx.x;

    if (blk < C_SZ / 4) {
        const int c = blk * 4 + wid;
        const size_t rb = (size_t)c * D_SZ + lane * 8;
        float e2v[8], e1v[8], pv[8];
        *(float4*)&e2v[0] = *(const float4*)(ex2 + rb);
        *(float4*)&e2v[4] = *(const float4*)(ex2 + rb + 4);
        *(float4*)&e1v[0] = *(const float4*)(ex1 + rb);
        *(float4*)&e1v[4] = *(const float4*)(ex1 + rb + 4);
        *(float4*)&pv[0]  = *(const float4*)(protos + rb);
        *(float4*)&pv[4]  = *(const float4*)(protos + rb + 4);
        const float N = (float)cls_num[c];

        float v[8], mn = FLT_MAX;
        #pragma unroll
        for (int k = 0; k < 8; k++) {
            v[k] = sqrtf(N * e2v[k] * e2v[k] - e1v[k] * e1v[k]);
            mn = fminf(mn, v[k]);
        }
        #pragma unroll
        for (int off = 1; off < 64; off <<= 1) mn = fminf(mn, __shfl_xor(mn, off));

        float ev[8], s = 0.f;
        #pragma unroll
        for (int k = 0; k < 8; k++) { ev[k] = expf(mn - v[k]); s += ev[k]; }
        #pragma unroll
        for (int off = 1; off < 64; off <<= 1) s += __shfl_xor(s, off);
        const float inv = 1.0f / s;

        float w1[8], w2[8], t = 0.f;
        #pragma unroll
        for (int k = 0; k < 8; k++) {
            const float rdv = ev[k] * inv;
            w1[k] = rdv;
            w2[k] = -2.0f * rdv * pv[k];
            t = fmaf(rdv * pv[k], pv[k], t);
        }
        float* wr = W + (size_t)c * K2 + lane * 8;
        *(float4*)(wr)              = *(float4*)&w1[0];
        *(float4*)(wr + 4)          = *(float4*)&w1[4];
        *(float4*)(wr + D_SZ)       = *(float4*)&w2[0];
        *(float4*)(wr + D_SZ + 4)   = *(float4*)&w2[4];
        #pragma unroll
        for (int off = 1; off < 64; off <<= 1) t += __shfl_xor(t, off);
        if (lane == 0) t3[c] = t;
    } else {
        const int b = (blk - C_SZ / 4) * 4 + wid;
        const size_t rb = (size_t)b * D_SZ + lane * 8;
        float xv[8], xs[8];
        *(float4*)&xv[0] = *(const float4*)(x + rb);
        *(float4*)&xv[4] = *(const float4*)(x + rb + 4);
        #pragma unroll
        for (int k = 0; k < 8; k++) xs[k] = xv[k] * xv[k];
        float* ar = A + (size_t)b * K2 + lane * 8;
        *(float4*)(ar)            = *(float4*)&xs[0];
        *(float4*)(ar + 4)        = *(float4*)&xs[4];
        *(float4*)(ar + D_SZ)     = *(float4*)&xv[0];
        *(float4*)(ar + D_SZ + 4) = *(float4*)&xv[4];
    }
}

// ---------------------------------------------------------------------------
// GEMM: part[z][b][c] = sum_{k in z-chunk} A[b,k]*W[c,k]
// 64x64 tile, BK=32, 256 threads, 4x4 micro-tile, split-K=4.
// Grid: 16(cTiles) x 8(bTiles) x 4(K) = 512 blocks -> 2 blocks/CU, 8 waves/CU.
// ---------------------------------------------------------------------------
#define TM 64
#define TN 64
#define KB 32

__global__ __launch_bounds__(256) void gemm_kernel(const float* __restrict__ A,
                                                   const float* __restrict__ W,
                                                   float* __restrict__ part) {
    __shared__ float as[KB][TM + 4];   // stride 68 floats: 16B-aligned cols, 2-way banks
    __shared__ float wsm[KB][TN + 4];

    const int tid = threadIdx.x;
    const int tx = tid & 15;           // c direction (x4)
    const int ty = tid >> 4;           // b direction (x4)
    const int c0 = blockIdx.x * TN;
    const int b0 = blockIdx.y * TM;
    const int kz = blockIdx.z;

    float acc[4][4] = {};

    for (int k0 = kz * KSPLIT; k0 < (kz + 1) * KSPLIT; k0 += KB) {
        #pragma unroll
        for (int i = 0; i < 2; i++) {
            const int f = tid + i * 256;
            const int row = f >> 3;
            const int col = (f & 7) * 4;
            float4 va = *(const float4*)(A + (size_t)(b0 + row) * K2 + k0 + col);
            as[col + 0][row] = va.x; as[col + 1][row] = va.y;
            as[col + 2][row] = va.z; as[col + 3][row] = va.w;
            const int cc = c0 + row;
            float4 vw = make_float4(0.f, 0.f, 0.f, 0.f);
            if (cc < C_SZ) vw = *(const float4*)(W + (size_t)cc * K2 + k0 + col);
            wsm[col + 0][row] = vw.x; wsm[col + 1][row] = vw.y;
            wsm[col + 2][row] = vw.z; wsm[col + 3][row] = vw.w;
        }
        __syncthreads();

        #pragma unroll
        for (int kk = 0; kk < KB; kk++) {
            float4 av4 = *(const float4*)&as[kk][ty * 4];
            float4 wv4 = *(const float4*)&wsm[kk][tx * 4];
            const float a[4] = {av4.x, av4.y, av4.z, av4.w};
            const float w[4] = {wv4.x, wv4.y, wv4.z, wv4.w};
            #pragma unroll
            for (int i = 0; i < 4; i++)
                #pragma unroll
                for (int j = 0; j < 4; j++)
                    acc[i][j] = fmaf(a[i], w[j], acc[i][j]);
        }
        __syncthreads();
    }

    float* o = part + (size_t)kz * BC;
    #pragma unroll
    for (int i = 0; i < 4; i++) {
        const int b = b0 + ty * 4 + i;
        const int c = c0 + tx * 4;
        if (c + 3 < C_SZ) {
            float4 v = {acc[i][0], acc[i][1], acc[i][2], acc[i][3]};
            *(float4*)(o + (size_t)b * C_SZ + c) = v;
        } else {
            #pragma unroll
            for (int j = 0; j < 4; j++)
                if (c + j < C_SZ) o[(size_t)b * C_SZ + c + j] = acc[i][j];
        }
    }
}

// ---------------------------------------------------------------------------
// Top-K: per row, sum split-K partials + t3, then 10x butterfly min with
// index tie-break (lower index wins == lax.top_k stability).
// out[0..B): predict (float-encoded int), out[B..): topk_conf [B][K]
// ---------------------------------------------------------------------------
__global__ __launch_bounds__(256) void topk_kernel(const float* __restrict__ ws,
                                                   const int* __restrict__ proto_label,
                                                   float* __restrict__ out) {
    const float* part = ws + PART_OFF;
    const float* t3   = ws + T3_OFF;
    const int wid = threadIdx.x >> 6;
    const int lane = threadIdx.x & 63;
    const int b = blockIdx.x * 4 + wid;

    float vals[16];
    #pragma unroll
    for (int j = 0; j < 16; j++) {
        const int c = lane + j * 64;
        if (c < C_SZ) {
            const size_t idx = (size_t)b * C_SZ + c;
            vals[j] = t3[c] + part[idx] + part[BC + idx]
                    + part[2 * (size_t)BC + idx] + part[3 * (size_t)BC + idx];
        } else {
            vals[j] = FLT_MAX;
        }
    }

    float kv[K_TOP];
    int ki[K_TOP];
    for (int t = 0; t < K_TOP; t++) {
        float bv = FLT_MAX;
        int bi = 0x7fffffff;
        #pragma unroll
        for (int j = 0; j < 16; j++) {
            const int c = lane + j * 64;
            if (vals[j] < bv) { bv = vals[j]; bi = c; }
        }
        #pragma unroll
        for (int off = 1; off < 64; off <<= 1) {
            const float ov = __shfl_xor(bv, off);
            const int oi = __shfl_xor(bi, off);
            if (ov < bv || (ov == bv && oi < bi)) { bv = ov; bi = oi; }
        }
        kv[t] = bv;
        ki[t] = bi;
        if ((bi & 63) == lane) vals[bi >> 6] = FLT_MAX;
    }

    if (lane == 0) {
        float S = 0.f;
        #pragma unroll
        for (int t = 0; t < K_TOP; t++) S += kv[t];
        float conf[K_TOP];
        #pragma unroll
        for (int t = 0; t < K_TOP; t++) {
            conf[t] = S / kv[t];
            out[B_SZ + b * K_TOP + t] = conf[t];
        }
        int best = 0;
        for (int t = 1; t < K_TOP; t++)
            if (conf[t] > conf[best]) best = t;
        out[b] = (float)proto_label[ki[best]];
    }
}

extern "C" void kernel_launch(void* const* d_in, const int* in_sizes, int n_in,
                              void* d_out, int out_size, void* d_ws, size_t ws_size,
                              hipStream_t stream) {
    const float* x           = (const float*)d_in[0];
    const float* protos      = (const float*)d_in[1];
    const float* ex2         = (const float*)d_in[2];
    const float* ex1         = (const float*)d_in[3];
    const int*   cls_num     = (const int*)d_in[4];
    const int*   proto_label = (const int*)d_in[5];

    float* ws  = (float*)d_ws;
    float* out = (float*)d_out;

    prep_kernel<<<C_SZ / 4 + B_SZ / 4, 256, 0, stream>>>(x, protos, ex2, ex1,
                                                         cls_num, ws);

    dim3 g2((C_SZ + TN - 1) / TN, B_SZ / TM, NSPLIT);   // 16 x 8 x 4 = 512
    gemm_kernel<<<g2, 256, 0, stream>>>(ws + A_OFF, ws + W_OFF, ws + PART_OFF);

    topk_kernel<<<B_SZ / 4, 256, 0, stream>>>(ws, proto_label, out);
}